// Round 2
// baseline (167.076 us; speedup 1.0000x reference)
//
#include <hip/hip_runtime.h>

// QuantumLayer: 4-qubit, 4-layer VQC over batch B.
// R8: SCALAR redesign — 1 batch element per thread, pure v_fma_f32.
//  Rationale: R6(3 waves) == R7(4 waves) == ~32 us kernel -> issue-bound,
//  not latency-bound. Hand-counted pk-op floor (12.3 us @ 4cyc/pk) is 2.6x
//  below observed; suspects are v_pk_fma_f32 rate (possibly 8 cyc on gfx950)
//  and v2f extract/insert codegen overhead. Scalar v_fma_f32 is a MEASURED
//  2 cyc/wave64 (m07) — per-element FLOPs identical, so this either wins ~2x
//  or ties; a tie falsifies the packing hypothesis cleanly.
//  Kept from R6/R7: fused precompute (M = RZ*RY in LDS), layer-3 RZ dropped
//  (exact), full unroll (CNOTs = register renames), butterfly measurement.
//  Gate quads now float4 in LDS -> one ds_read_b128 per make_g2.
// State indexing: flat k = w0*8 + w1*4 + w2*2 + w3  (wire i -> bit (3-i)).

// G = M * RX(cx, sx) is SU(2): G = [[g, d], [-conj(d), conj(g)]].
// Msh quad = {ar, ai, br, bi} (M = [[a, b], [-conj(b), conj(a)]]).
__device__ __forceinline__ void make_g2(const float4* Msh, int idx,
                                        float c, float s,
                                        float& gr, float& gi, float& dr, float& di) {
  float4 m = Msh[idx];  // ds_read_b128, wave-uniform broadcast
  gr = m.x * c + m.w * s;
  gi = m.y * c - m.z * s;
  dr = m.y * s + m.z * c;
  di = m.w * c - m.x * s;
}

// Layer-3 variant: RZ == I there, so M = RY is REAL (ai = bi = 0).
__device__ __forceinline__ void make_g2_real(const float4* Msh, int idx,
                                             float c, float s,
                                             float& gr, float& gi, float& dr, float& di) {
  float4 m = Msh[idx];
  gr = m.x * c;
  gi = -(m.z * s);
  dr = m.z * c;
  di = -(m.x * s);
}

// Apply SU(2) gate [[g,d],[-conj(d),conj(g)]] on wire W (bit 3-W).
template <int W>
__device__ __forceinline__ void apply_su2(float (&sr)[16], float (&si)[16],
                                          float gr, float gi, float dr, float di) {
  constexpr int stride = 8 >> W;
#pragma unroll
  for (int base = 0; base < 16; base += 2 * stride) {
#pragma unroll
    for (int j = 0; j < stride; ++j) {
      const int k0 = base + j, k1 = k0 + stride;
      float a0r = sr[k0], a0i = si[k0], a1r = sr[k1], a1i = si[k1];
      sr[k0] = gr * a0r - gi * a0i + dr * a1r - di * a1i;
      si[k0] = gr * a0i + gi * a0r + dr * a1i + di * a1r;
      sr[k1] = gr * a1r + gi * a1i - dr * a0r - di * a0i;
      si[k1] = gr * a1i - gi * a1r - dr * a0i + di * a0r;
    }
  }
}

// CNOT(control C, target T): pure register permutation (fully unrolled).
template <int C, int T>
__device__ __forceinline__ void apply_cnot_(float (&sr)[16], float (&si)[16]) {
  constexpr int cb = 8 >> C, tb = 8 >> T;
#pragma unroll
  for (int k = 0; k < 16; ++k) {
    if ((k & cb) && !(k & tb)) {
      const int k2 = k | tb;
      float tr = sr[k]; sr[k] = sr[k2]; sr[k2] = tr;
      float ti = si[k]; si[k] = si[k2]; si[k2] = ti;
    }
  }
}

__global__ __launch_bounds__(256, 6) void qlayer_main(const float* __restrict__ x,
                                                      const float* __restrict__ w,
                                                      float* __restrict__ out) {
  // ---- Fused precompute: M = RZ(pz)*RY(py) per (layer, wire); layer 3 uses
  // RZ = I (exact: diagonal phase before the final CNOT block is
  // probability-invariant). float4 quads {ar,ai,br,bi} in LDS (256 B). ----
  __shared__ float4 Msh[16];
  int tid = threadIdx.x;
  if (tid < 16) {
    int l = tid >> 2, q = tid & 3;
    float ay = 0.5f * w[8 * l + q];                       // RY angle /2
    float az = (l == 3) ? 0.0f : 0.5f * w[8 * l + 4 + q]; // RZ angle /2 (I on l=3)
    float cy, sy, cz, sz;
    __sincosf(ay, &sy, &cy);
    __sincosf(az, &sz, &cz);
    Msh[tid] = make_float4(cz * cy, -sz * cy, -cz * sy, sz * sy);
  }

  int t = blockIdx.x * blockDim.x + tid;  // owns batch element t
  float4 xv = reinterpret_cast<const float4*>(x)[t];
  float cx[4], sx[4];
  __sincosf(0.5f * xv.x, &sx[0], &cx[0]);
  __sincosf(0.5f * xv.y, &sx[1], &cx[1]);
  __sincosf(0.5f * xv.z, &sx[2], &cx[2]);
  __sincosf(0.5f * xv.w, &sx[3], &cx[3]);

  __syncthreads();  // Msh ready

  float sr[16], si[16];

  // ---- Layer 0 on |0000>: product state, built IN-PLACE LSB-first.
  // bit=0 branch * g; bit=1 branch * -conj(d) = (-dr,+di):
  //   re = -dr*ar - di*ai,   im = di*ar - dr*ai. ----
  {
    float gr, gi, dr, di;
    make_g2(Msh, 3, cx[3], sx[3], gr, gi, dr, di);
    sr[0] = gr;  si[0] = gi;
    sr[1] = -dr; si[1] = di;
    make_g2(Msh, 2, cx[2], sx[2], gr, gi, dr, di);
#pragma unroll
    for (int k = 1; k >= 0; --k) {
      float ar_ = sr[k], ai_ = si[k];
      sr[k + 2] = -(dr * ar_) - di * ai_;
      si[k + 2] = di * ar_ - dr * ai_;
      sr[k]     = gr * ar_ - gi * ai_;
      si[k]     = gr * ai_ + gi * ar_;
    }
    make_g2(Msh, 1, cx[1], sx[1], gr, gi, dr, di);
#pragma unroll
    for (int k = 3; k >= 0; --k) {
      float ar_ = sr[k], ai_ = si[k];
      sr[k + 4] = -(dr * ar_) - di * ai_;
      si[k + 4] = di * ar_ - dr * ai_;
      sr[k]     = gr * ar_ - gi * ai_;
      si[k]     = gr * ai_ + gi * ar_;
    }
    make_g2(Msh, 0, cx[0], sx[0], gr, gi, dr, di);
#pragma unroll
    for (int k = 7; k >= 0; --k) {
      float ar_ = sr[k], ai_ = si[k];
      sr[k + 8] = -(dr * ar_) - di * ai_;
      si[k + 8] = di * ar_ - dr * ai_;
      sr[k]     = gr * ar_ - gi * ai_;
      si[k]     = gr * ai_ + gi * ar_;
    }
  }
  apply_cnot_<2, 3>(sr, si);
  apply_cnot_<1, 2>(sr, si);
  apply_cnot_<0, 1>(sr, si);
  apply_cnot_<3, 0>(sr, si);

  // ---- Layers 1..2 (fully unrolled: CNOTs stay register renames) ----
#pragma unroll
  for (int l = 1; l < 3; ++l) {
    float gr, gi, dr, di;
    make_g2(Msh, l * 4 + 0, cx[0], sx[0], gr, gi, dr, di);
    apply_su2<0>(sr, si, gr, gi, dr, di);
    make_g2(Msh, l * 4 + 1, cx[1], sx[1], gr, gi, dr, di);
    apply_su2<1>(sr, si, gr, gi, dr, di);
    make_g2(Msh, l * 4 + 2, cx[2], sx[2], gr, gi, dr, di);
    apply_su2<2>(sr, si, gr, gi, dr, di);
    make_g2(Msh, l * 4 + 3, cx[3], sx[3], gr, gi, dr, di);
    apply_su2<3>(sr, si, gr, gi, dr, di);
    apply_cnot_<2, 3>(sr, si);
    apply_cnot_<1, 2>(sr, si);
    apply_cnot_<0, 1>(sr, si);
    apply_cnot_<3, 0>(sr, si);
  }

  // ---- Layer 3: M real (RZ folded out) ----
  {
    float gr, gi, dr, di;
    make_g2_real(Msh, 12, cx[0], sx[0], gr, gi, dr, di);
    apply_su2<0>(sr, si, gr, gi, dr, di);
    make_g2_real(Msh, 13, cx[1], sx[1], gr, gi, dr, di);
    apply_su2<1>(sr, si, gr, gi, dr, di);
    make_g2_real(Msh, 14, cx[2], sx[2], gr, gi, dr, di);
    apply_su2<2>(sr, si, gr, gi, dr, di);
    make_g2_real(Msh, 15, cx[3], sx[3], gr, gi, dr, di);
    apply_su2<3>(sr, si, gr, gi, dr, di);
    apply_cnot_<2, 3>(sr, si);
    apply_cnot_<1, 2>(sr, si);
    apply_cnot_<0, 1>(sr, si);
    apply_cnot_<3, 0>(sr, si);
  }

  // ---- Measurement: fold |amp|^2 into the first butterfly level so state
  // regs die as consumed. o_i = sum_k p_k * (bit(3-i)?-1:+1). ----
  float s2[8], d2[8];
#pragma unroll
  for (int k = 0; k < 8; ++k) {
    float p0 = sr[2 * k]     * sr[2 * k]     + si[2 * k]     * si[2 * k];
    float p1 = sr[2 * k + 1] * sr[2 * k + 1] + si[2 * k + 1] * si[2 * k + 1];
    s2[k] = p0 + p1;
    d2[k] = p0 - p1;
  }
  float o3 = ((d2[0] + d2[1]) + (d2[2] + d2[3])) + ((d2[4] + d2[5]) + (d2[6] + d2[7]));
  float s4[4], d4[4];
#pragma unroll
  for (int k = 0; k < 4; ++k) {
    s4[k] = s2[2 * k] + s2[2 * k + 1];
    d4[k] = s2[2 * k] - s2[2 * k + 1];
  }
  float o2 = (d4[0] + d4[1]) + (d4[2] + d4[3]);
  float s8a = s4[0] + s4[1], s8b = s4[2] + s4[3];
  float d8a = s4[0] - s4[1], d8b = s4[2] - s4[3];
  float o1 = d8a + d8b;
  float o0 = s8a - s8b;

  reinterpret_cast<float4*>(out)[t] = make_float4(o0, o1, o2, o3);
}

extern "C" void kernel_launch(void* const* d_in, const int* in_sizes, int n_in,
                              void* d_out, int out_size, void* d_ws, size_t ws_size,
                              hipStream_t stream) {
  const float* x = (const float*)d_in[0];
  const float* w = (const float*)d_in[1];
  float* out = (float*)d_out;
  int nb = in_sizes[0] / 4;  // batch elements; B=524288

  int blocks = nb / 256;     // exact: 2048 blocks, 1 element/thread
  hipLaunchKernelGGL(qlayer_main, dim3(blocks), dim3(256), 0, stream, x, w, out);
}

// Round 3
// 155.081 us; speedup vs baseline: 1.0773x; 1.0773x over previous
//
#include <hip/hip_runtime.h>

// QuantumLayer: 4-qubit, 4-layer VQC over batch B.
// R9 = R8 scalar structure with the spill fixed: __launch_bounds__(256, 4).
//  R8 post-mortem: (256,6) capped VGPR at ~80, allocator demoted state to
//  scratch (VGPR_Count=40, FETCH 145 MB of spill traffic, kernel 32->115us).
//  Scalar needs ~60-75 VGPR; cap 128 leaves slack. R7 proved 4 waves/SIMD
//  is enough occupancy for this issue-bound kernel.
//  Theory retained: v_pk_fma_f32 is half the scalar FLOP rate (full-rate
//  would exceed the 157.3 TF spec), so pure v_fma_f32 at 2 cyc/wave64
//  should drop the kernel from ~32us toward the ~13us issue floor.
//  Kept: fused precompute (M = RZ*RY in LDS), layer-3 RZ dropped (exact),
//  full unroll (CNOTs = register renames), folded butterfly measurement.
// State indexing: flat k = w0*8 + w1*4 + w2*2 + w3  (wire i -> bit (3-i)).

// G = M * RX(cx, sx) is SU(2): G = [[g, d], [-conj(d), conj(g)]].
// Msh quad = {ar, ai, br, bi} (M = [[a, b], [-conj(b), conj(a)]]).
__device__ __forceinline__ void make_g2(const float4* Msh, int idx,
                                        float c, float s,
                                        float& gr, float& gi, float& dr, float& di) {
  float4 m = Msh[idx];  // ds_read_b128, wave-uniform broadcast
  gr = m.x * c + m.w * s;
  gi = m.y * c - m.z * s;
  dr = m.y * s + m.z * c;
  di = m.w * c - m.x * s;
}

// Layer-3 variant: RZ == I there, so M = RY is REAL (ai = bi = 0).
__device__ __forceinline__ void make_g2_real(const float4* Msh, int idx,
                                             float c, float s,
                                             float& gr, float& gi, float& dr, float& di) {
  float4 m = Msh[idx];
  gr = m.x * c;
  gi = -(m.z * s);
  dr = m.z * c;
  di = -(m.x * s);
}

// Apply SU(2) gate [[g,d],[-conj(d),conj(g)]] on wire W (bit 3-W).
template <int W>
__device__ __forceinline__ void apply_su2(float (&sr)[16], float (&si)[16],
                                          float gr, float gi, float dr, float di) {
  constexpr int stride = 8 >> W;
#pragma unroll
  for (int base = 0; base < 16; base += 2 * stride) {
#pragma unroll
    for (int j = 0; j < stride; ++j) {
      const int k0 = base + j, k1 = k0 + stride;
      float a0r = sr[k0], a0i = si[k0], a1r = sr[k1], a1i = si[k1];
      sr[k0] = gr * a0r - gi * a0i + dr * a1r - di * a1i;
      si[k0] = gr * a0i + gi * a0r + dr * a1i + di * a1r;
      sr[k1] = gr * a1r + gi * a1i - dr * a0r - di * a0i;
      si[k1] = gr * a1i - gi * a1r - dr * a0i + di * a0r;
    }
  }
}

// CNOT(control C, target T): pure register permutation (fully unrolled).
template <int C, int T>
__device__ __forceinline__ void apply_cnot_(float (&sr)[16], float (&si)[16]) {
  constexpr int cb = 8 >> C, tb = 8 >> T;
#pragma unroll
  for (int k = 0; k < 16; ++k) {
    if ((k & cb) && !(k & tb)) {
      const int k2 = k | tb;
      float tr = sr[k]; sr[k] = sr[k2]; sr[k2] = tr;
      float ti = si[k]; si[k] = si[k2]; si[k2] = ti;
    }
  }
}

__global__ __launch_bounds__(256, 4) void qlayer_main(const float* __restrict__ x,
                                                      const float* __restrict__ w,
                                                      float* __restrict__ out) {
  // ---- Fused precompute: M = RZ(pz)*RY(py) per (layer, wire); layer 3 uses
  // RZ = I (exact: diagonal phase before the final CNOT block is
  // probability-invariant). float4 quads {ar,ai,br,bi} in LDS (256 B). ----
  __shared__ float4 Msh[16];
  int tid = threadIdx.x;
  if (tid < 16) {
    int l = tid >> 2, q = tid & 3;
    float ay = 0.5f * w[8 * l + q];                       // RY angle /2
    float az = (l == 3) ? 0.0f : 0.5f * w[8 * l + 4 + q]; // RZ angle /2 (I on l=3)
    float cy, sy, cz, sz;
    __sincosf(ay, &sy, &cy);
    __sincosf(az, &sz, &cz);
    Msh[tid] = make_float4(cz * cy, -sz * cy, -cz * sy, sz * sy);
  }

  int t = blockIdx.x * blockDim.x + tid;  // owns batch element t
  float4 xv = reinterpret_cast<const float4*>(x)[t];
  float cx[4], sx[4];
  __sincosf(0.5f * xv.x, &sx[0], &cx[0]);
  __sincosf(0.5f * xv.y, &sx[1], &cx[1]);
  __sincosf(0.5f * xv.z, &sx[2], &cx[2]);
  __sincosf(0.5f * xv.w, &sx[3], &cx[3]);

  __syncthreads();  // Msh ready

  float sr[16], si[16];

  // ---- Layer 0 on |0000>: product state, built IN-PLACE LSB-first.
  // bit=0 branch * g; bit=1 branch * -conj(d) = (-dr,+di):
  //   re = -dr*ar - di*ai,   im = di*ar - dr*ai. ----
  {
    float gr, gi, dr, di;
    make_g2(Msh, 3, cx[3], sx[3], gr, gi, dr, di);
    sr[0] = gr;  si[0] = gi;
    sr[1] = -dr; si[1] = di;
    make_g2(Msh, 2, cx[2], sx[2], gr, gi, dr, di);
#pragma unroll
    for (int k = 1; k >= 0; --k) {
      float ar_ = sr[k], ai_ = si[k];
      sr[k + 2] = -(dr * ar_) - di * ai_;
      si[k + 2] = di * ar_ - dr * ai_;
      sr[k]     = gr * ar_ - gi * ai_;
      si[k]     = gr * ai_ + gi * ar_;
    }
    make_g2(Msh, 1, cx[1], sx[1], gr, gi, dr, di);
#pragma unroll
    for (int k = 3; k >= 0; --k) {
      float ar_ = sr[k], ai_ = si[k];
      sr[k + 4] = -(dr * ar_) - di * ai_;
      si[k + 4] = di * ar_ - dr * ai_;
      sr[k]     = gr * ar_ - gi * ai_;
      si[k]     = gr * ai_ + gi * ar_;
    }
    make_g2(Msh, 0, cx[0], sx[0], gr, gi, dr, di);
#pragma unroll
    for (int k = 7; k >= 0; --k) {
      float ar_ = sr[k], ai_ = si[k];
      sr[k + 8] = -(dr * ar_) - di * ai_;
      si[k + 8] = di * ar_ - dr * ai_;
      sr[k]     = gr * ar_ - gi * ai_;
      si[k]     = gr * ai_ + gi * ar_;
    }
  }
  apply_cnot_<2, 3>(sr, si);
  apply_cnot_<1, 2>(sr, si);
  apply_cnot_<0, 1>(sr, si);
  apply_cnot_<3, 0>(sr, si);

  // ---- Layers 1..2 (fully unrolled: CNOTs stay register renames) ----
#pragma unroll
  for (int l = 1; l < 3; ++l) {
    float gr, gi, dr, di;
    make_g2(Msh, l * 4 + 0, cx[0], sx[0], gr, gi, dr, di);
    apply_su2<0>(sr, si, gr, gi, dr, di);
    make_g2(Msh, l * 4 + 1, cx[1], sx[1], gr, gi, dr, di);
    apply_su2<1>(sr, si, gr, gi, dr, di);
    make_g2(Msh, l * 4 + 2, cx[2], sx[2], gr, gi, dr, di);
    apply_su2<2>(sr, si, gr, gi, dr, di);
    make_g2(Msh, l * 4 + 3, cx[3], sx[3], gr, gi, dr, di);
    apply_su2<3>(sr, si, gr, gi, dr, di);
    apply_cnot_<2, 3>(sr, si);
    apply_cnot_<1, 2>(sr, si);
    apply_cnot_<0, 1>(sr, si);
    apply_cnot_<3, 0>(sr, si);
  }

  // ---- Layer 3: M real (RZ folded out) ----
  {
    float gr, gi, dr, di;
    make_g2_real(Msh, 12, cx[0], sx[0], gr, gi, dr, di);
    apply_su2<0>(sr, si, gr, gi, dr, di);
    make_g2_real(Msh, 13, cx[1], sx[1], gr, gi, dr, di);
    apply_su2<1>(sr, si, gr, gi, dr, di);
    make_g2_real(Msh, 14, cx[2], sx[2], gr, gi, dr, di);
    apply_su2<2>(sr, si, gr, gi, dr, di);
    make_g2_real(Msh, 15, cx[3], sx[3], gr, gi, dr, di);
    apply_su2<3>(sr, si, gr, gi, dr, di);
    apply_cnot_<2, 3>(sr, si);
    apply_cnot_<1, 2>(sr, si);
    apply_cnot_<0, 1>(sr, si);
    apply_cnot_<3, 0>(sr, si);
  }

  // ---- Measurement: fold |amp|^2 into the first butterfly level so state
  // regs die as consumed. o_i = sum_k p_k * (bit(3-i)?-1:+1). ----
  float s2[8], d2[8];
#pragma unroll
  for (int k = 0; k < 8; ++k) {
    float p0 = sr[2 * k]     * sr[2 * k]     + si[2 * k]     * si[2 * k];
    float p1 = sr[2 * k + 1] * sr[2 * k + 1] + si[2 * k + 1] * si[2 * k + 1];
    s2[k] = p0 + p1;
    d2[k] = p0 - p1;
  }
  float o3 = ((d2[0] + d2[1]) + (d2[2] + d2[3])) + ((d2[4] + d2[5]) + (d2[6] + d2[7]));
  float s4[4], d4[4];
#pragma unroll
  for (int k = 0; k < 4; ++k) {
    s4[k] = s2[2 * k] + s2[2 * k + 1];
    d4[k] = s2[2 * k] - s2[2 * k + 1];
  }
  float o2 = (d4[0] + d4[1]) + (d4[2] + d4[3]);
  float s8a = s4[0] + s4[1], s8b = s4[2] + s4[3];
  float d8a = s4[0] - s4[1], d8b = s4[2] - s4[3];
  float o1 = d8a + d8b;
  float o0 = s8a - s8b;

  reinterpret_cast<float4*>(out)[t] = make_float4(o0, o1, o2, o3);
}

extern "C" void kernel_launch(void* const* d_in, const int* in_sizes, int n_in,
                              void* d_out, int out_size, void* d_ws, size_t ws_size,
                              hipStream_t stream) {
  const float* x = (const float*)d_in[0];
  const float* w = (const float*)d_in[1];
  float* out = (float*)d_out;
  int nb = in_sizes[0] / 4;  // batch elements; B=524288

  int blocks = nb / 256;     // exact: 2048 blocks, 1 element/thread
  hipLaunchKernelGGL(qlayer_main, dim3(blocks), dim3(256), 0, stream, x, w, out);
}